// Round 5
// baseline (815.439 us; speedup 1.0000x reference)
//
#include <hip/hip_runtime.h>

typedef unsigned int u32;
typedef unsigned short u16;
typedef __attribute__((ext_vector_type(8))) short short8;
typedef __attribute__((ext_vector_type(4))) float f32x4;

#define DD 128
#define RREL 8
#define NKT 9      // k-tiles: [root | W0..W7], 128 k each
#define SCAN_CHUNK 4096

static __device__ __forceinline__ u16 f2bf(float f) {
  u32 u = __builtin_bit_cast(u32, f);
  u32 r = (u + 0x7fffu + ((u >> 16) & 1u)) >> 16;
  return (u16)r;
}
static __device__ __forceinline__ float bflo(u32 v) { return __builtin_bit_cast(float, v << 16); }
static __device__ __forceinline__ float bfhi(u32 v) { return __builtin_bit_cast(float, v & 0xffff0000u); }

// ---- build pre-swizzled transposed weights for linear global_load_lds staging.
// wt[l][kt][pos] (16B chunks): pos = col*16 + cbx holds chunk (col, cb=cbx^(col&7)),
// chunk (col,cb) = 8 bf16 of column `col` at k = kt*128 + cb*8 .. +8, k-space = [root | W0..W7].
__global__ __launch_bounds__(256) void k_convw(const float* __restrict__ W,
                                               const float* __restrict__ root,
                                               uint4* __restrict__ wt) {
  int t = blockIdx.x * 256 + threadIdx.x;
  if (t >= 2 * NKT * 2048) return;
  int l = t / (NKT * 2048);
  int rem = t - l * (NKT * 2048);
  int kt = rem >> 11;
  int pos = rem & 2047;
  int col = pos >> 4;
  int cbx = pos & 15;
  int cb = cbx ^ (col & 7);
  int k0 = kt * DD + cb * 8;
  u16 vals[8];
#pragma unroll
  for (int i = 0; i < 8; ++i) {
    int k = k0 + i;
    float v;
    if (k < DD) {
      v = root[(size_t)l * DD * DD + k * DD + col];
    } else {
      int km = k - DD;
      v = W[((size_t)l * RREL + (km >> 7)) * DD * DD + (size_t)(km & 127) * DD + col];
    }
    vals[i] = f2bf(v);
  }
  wt[t] = *(uint4*)vals;
}

// ---- h0 = bf16(emb[x]) dense [N][128]
__global__ __launch_bounds__(256) void k_gather(const int* __restrict__ x,
                                                const float* __restrict__ emb,
                                                u16* __restrict__ h0, int N) {
  int t = blockIdx.x * 256 + threadIdx.x;
  if (t >= N * 16) return;
  int node = t >> 4, part = t & 15;
  const float4* e4 = (const float4*)(emb + (size_t)x[node] * DD + part * 8);
  float4 f0 = e4[0], f1 = e4[1];
  uint4 u;
  u.x = (u32)f2bf(f0.x) | ((u32)f2bf(f0.y) << 16);
  u.y = (u32)f2bf(f0.z) | ((u32)f2bf(f0.w) << 16);
  u.z = (u32)f2bf(f1.x) | ((u32)f2bf(f1.y) << 16);
  u.w = (u32)f2bf(f1.z) | ((u32)f2bf(f1.w) << 16);
  *(uint4*)(h0 + (size_t)node * DD + part * 8) = u;
}

// ---- histogram over segments seg = dst*8 + etype, 4 edges/thread for ILP
__global__ __launch_bounds__(256) void k_hist(const int* __restrict__ ei,
                                              const int* __restrict__ et,
                                              int* __restrict__ cnt, int E) {
  int base = (blockIdx.x * 256 + threadIdx.x) * 4;
  if (base + 3 < E) {
    int4 d4 = *(const int4*)(ei + E + base);
    int4 t4 = *(const int4*)(et + base);
    atomicAdd(&cnt[d4.x * 8 + t4.x], 1);
    atomicAdd(&cnt[d4.y * 8 + t4.y], 1);
    atomicAdd(&cnt[d4.z * 8 + t4.z], 1);
    atomicAdd(&cnt[d4.w * 8 + t4.w], 1);
  } else {
    for (int e = base; e < E; ++e) atomicAdd(&cnt[ei[E + e] * 8 + et[e]], 1);
  }
}

__global__ __launch_bounds__(256) void k_scan_reduce(const int* __restrict__ cnt,
                                                     int* __restrict__ blksum, int nseg) {
  __shared__ int s[256];
  int b = blockIdx.x, t = threadIdx.x;
  int base = b * SCAN_CHUNK;
  int sum = 0;
  for (int i = 0; i < 16; ++i) {
    int idx = base + i * 256 + t;
    if (idx < nseg) sum += cnt[idx];
  }
  s[t] = sum;
  __syncthreads();
  for (int st = 128; st > 0; st >>= 1) {
    if (t < st) s[t] += s[t + st];
    __syncthreads();
  }
  if (t == 0) blksum[b] = s[0];
}

__global__ void k_scan_top(int* __restrict__ blksum, int nblk, int* __restrict__ off,
                           int nseg, int E) {
  if (threadIdx.x == 0 && blockIdx.x == 0) {
    int run = 0;
    for (int b = 0; b < nblk; ++b) { int v = blksum[b]; blksum[b] = run; run += v; }
    off[nseg] = E;
  }
}

__global__ __launch_bounds__(256) void k_scan_write(const int* __restrict__ cnt,
                                                    const int* __restrict__ blksum,
                                                    int* __restrict__ off, int nseg) {
  __shared__ int s[256];
  int b = blockIdx.x, t = threadIdx.x;
  int base = b * SCAN_CHUNK + t * 16;
  int v[16];
  int sum = 0;
#pragma unroll
  for (int i = 0; i < 16; ++i) {
    int idx = base + i;
    v[i] = (idx < nseg) ? cnt[idx] : 0;
    sum += v[i];
  }
  s[t] = sum;
  __syncthreads();
  for (int st = 1; st < 256; st <<= 1) {
    int add = (t >= st) ? s[t - st] : 0;
    __syncthreads();
    s[t] += add;
    __syncthreads();
  }
  int run = blksum[b] + s[t] - sum;
#pragma unroll
  for (int i = 0; i < 16; ++i) {
    int idx = base + i;
    if (idx < nseg) off[idx] = run;
    run += v[i];
  }
}

// ---- scatter: fill starts as a copy of off; pos = atomicAdd(&fill[seg],1). 4 edges/thread.
__global__ __launch_bounds__(256) void k_scatter(const int* __restrict__ ei,
                                                 const int* __restrict__ et,
                                                 int* __restrict__ fill,
                                                 int* __restrict__ sorted, int E) {
  int base = (blockIdx.x * 256 + threadIdx.x) * 4;
  if (base + 3 < E) {
    int4 s4 = *(const int4*)(ei + base);
    int4 d4 = *(const int4*)(ei + E + base);
    int4 t4 = *(const int4*)(et + base);
    int p0 = atomicAdd(&fill[d4.x * 8 + t4.x], 1);
    int p1 = atomicAdd(&fill[d4.y * 8 + t4.y], 1);
    int p2 = atomicAdd(&fill[d4.z * 8 + t4.z], 1);
    int p3 = atomicAdd(&fill[d4.w * 8 + t4.w], 1);
    sorted[p0] = s4.x;
    sorted[p1] = s4.y;
    sorted[p2] = s4.z;
    sorted[p3] = s4.w;
  } else {
    for (int e = base; e < E; ++e) {
      int pos = atomicAdd(&fill[ei[E + e] * 8 + et[e]], 1);
      sorted[pos] = ei[e];
    }
  }
}

static __device__ __forceinline__ void add8(float* a, uint4 v) {
  a[0] += bflo(v.x); a[1] += bfhi(v.x);
  a[2] += bflo(v.y); a[3] += bfhi(v.y);
  a[4] += bflo(v.z); a[5] += bfhi(v.z);
  a[6] += bflo(v.w); a[7] += bfhi(v.w);
}

// ---- fused layer: out[row] = relu( [h | mean_r(h[src])] @ Wcat + bias )
// Phase 1 (no barriers): gather ALL 9 A-fragments (root + 8 relation means) into
// registers, accumulating directly in MFMA A-fragment layout. Phase 2: 9 k-tiles
// of pure MFMA with double-buffered global_load_lds B staging (pre-swizzled wt).
template <bool LAST>
__global__ __launch_bounds__(512, 2) void k_fused(const u16* __restrict__ hin,
                                                  const int* __restrict__ off,
                                                  const int* __restrict__ sorted,
                                                  const uint4* __restrict__ wt,
                                                  const float* __restrict__ bias,
                                                  u16* __restrict__ hout,
                                                  float* __restrict__ dout, int M) {
  __shared__ uint4 ldsB[2][2048];  // 2 x 32KB
  int tid = threadIdx.x, wave = tid >> 6, lane = tid & 63;
  int p = lane & 15, q = lane >> 4;
  int row = blockIdx.x * 128 + wave * 16 + p;
  int arc = row < M ? row : M - 1;

#define STAGE(KT, BUF)                                                                   \
  do {                                                                                   \
    const uint4* gsrc = wt + (size_t)(KT) * 2048;                                        \
    _Pragma("unroll") for (int i_ = 0; i_ < 4; ++i_) {                                   \
      int cid_ = i_ * 512 + tid;                                                         \
      __builtin_amdgcn_global_load_lds(                                                  \
          (const __attribute__((address_space(1))) uint4*)(gsrc + cid_),                 \
          (__attribute__((address_space(3))) uint4*)&ldsB[BUF][cid_], 16, 0, 0);         \
    }                                                                                    \
  } while (0)

  STAGE(0, 0);  // B k-tile 0 stages during the whole gather phase

  // ---- phase 1: all A-fragments, barrier-free
  short8 afr[NKT][4];
  {
    const short8* ap = (const short8*)(hin + (size_t)arc * DD) + q;
#pragma unroll
    for (int kc = 0; kc < 4; ++kc) afr[0][kc] = ap[kc * 4];
  }
  int row8 = arc * 8;
  int4 oA = *(const int4*)(off + row8);
  int4 oB = *(const int4*)(off + row8 + 4);
  int oC = off[row8 + 8];
  int ov[9] = {oA.x, oA.y, oA.z, oA.w, oB.x, oB.y, oB.z, oB.w, oC};
#pragma unroll
  for (int r = 0; r < RREL; ++r) {
    int s = ov[r], e = ov[r + 1];
    float a[32];
#pragma unroll
    for (int i = 0; i < 32; ++i) a[i] = 0.f;
    int j = s;
    for (; j + 2 <= e; j += 2) {
      int s0 = sorted[j], s1 = sorted[j + 1];
      const uint4* h0p = (const uint4*)(hin + (size_t)s0 * DD) + q;
      const uint4* h1p = (const uint4*)(hin + (size_t)s1 * DD) + q;
      uint4 u0 = h0p[0], u1 = h0p[4], u2 = h0p[8], u3 = h0p[12];
      uint4 w0 = h1p[0], w1 = h1p[4], w2 = h1p[8], w3 = h1p[12];
      add8(a + 0, u0);  add8(a + 8, u1);  add8(a + 16, u2);  add8(a + 24, u3);
      add8(a + 0, w0);  add8(a + 8, w1);  add8(a + 16, w2);  add8(a + 24, w3);
    }
    if (j < e) {
      const uint4* h0p = (const uint4*)(hin + (size_t)sorted[j] * DD) + q;
      uint4 u0 = h0p[0], u1 = h0p[4], u2 = h0p[8], u3 = h0p[12];
      add8(a + 0, u0);  add8(a + 8, u1);  add8(a + 16, u2);  add8(a + 24, u3);
    }
    float norm = (e > s) ? 1.0f / (float)(e - s) : 0.f;
    u16 fr[32];
#pragma unroll
    for (int i = 0; i < 32; ++i) fr[i] = f2bf(a[i] * norm);
#pragma unroll
    for (int kc = 0; kc < 4; ++kc) afr[r + 1][kc] = *(const short8*)(fr + kc * 8);
  }

  // ---- phase 2: pure MFMA over 9 k-tiles, double-buffered B staging
  f32x4 acc[8];
#pragma unroll
  for (int c = 0; c < 8; ++c) acc[c] = (f32x4)0.f;
#pragma unroll
  for (int kt = 0; kt < NKT; ++kt) {
    int cur = kt & 1;
    __syncthreads();  // drains vmcnt -> buf[cur] staged; syncs reuse of buf[cur^1]
    if (kt + 1 < NKT) STAGE(kt + 1, cur ^ 1);
#pragma unroll
    for (int kc = 0; kc < 4; ++kc) {
      int chunk = kc * 4 + q;
#pragma unroll
      for (int c = 0; c < 8; ++c) {
        int col = c * 16 + p;
        const short8* bp = (const short8*)&ldsB[cur][col * 16 + (chunk ^ (col & 7))];
        acc[c] = __builtin_amdgcn_mfma_f32_16x16x32_bf16(afr[kt][kc], *bp, acc[c], 0, 0, 0);
      }
    }
  }
#undef STAGE

  int crow0 = blockIdx.x * 128 + wave * 16 + (q << 2);
#pragma unroll
  for (int c = 0; c < 8; ++c) {
    int col = c * 16 + p;
    float bv = bias[col];
#pragma unroll
    for (int i = 0; i < 4; ++i) {
      int rw = crow0 + i;
      if (rw < M) {
        float v = fmaxf(acc[c][i] + bv, 0.f);
        if (LAST) dout[(size_t)rw * DD + col] = v;
        else hout[(size_t)rw * DD + col] = f2bf(v);
      }
    }
  }
}

extern "C" void kernel_launch(void* const* d_in, const int* in_sizes, int n_in,
                              void* d_out, int out_size, void* d_ws, size_t ws_size,
                              hipStream_t stream) {
  const int* x = (const int*)d_in[0];
  const int* ei = (const int*)d_in[1];
  const int* et = (const int*)d_in[2];
  const float* emb = (const float*)d_in[3];
  const float* W = (const float*)d_in[4];
  const float* root = (const float*)d_in[5];
  const float* bias = (const float*)d_in[6];

  const int N = in_sizes[0];
  const int E = in_sizes[2];
  const int NSEG = N * RREL;

  size_t o = 0;
  auto al = [&](size_t b) { size_t r = o; o = (o + b + 255) & ~(size_t)255; return r; };
  size_t off_o = al(((size_t)NSEG + 1) * 4);
  size_t cnt_o = al((size_t)NSEG * 4);
  size_t fill_o = al((size_t)NSEG * 4);
  size_t sorted_o = al((size_t)E * 4);
  size_t blk_o = al(4096);
  size_t wt_o = al((size_t)2 * NKT * 2048 * 16);
  size_t h0_o = al((size_t)N * DD * 2);
  size_t h1_o = al((size_t)N * DD * 2);
  (void)h1_o;

  char* ws = (char*)d_ws;
  int* off = (int*)(ws + off_o);
  int* cnt = (int*)(ws + cnt_o);
  int* fill = (int*)(ws + fill_o);
  int* sorted = (int*)(ws + sorted_o);
  int* blks = (int*)(ws + blk_o);
  uint4* wt = (uint4*)(ws + wt_o);
  u16* h0 = (u16*)(ws + h0_o);
  u16* h1 = (u16*)(ws + h1_o);
  float* outf = (float*)d_out;

  // ---- prep
  k_convw<<<(2 * NKT * 2048 + 255) / 256, 256, 0, stream>>>(W, root, wt);
  k_gather<<<(N * 16 + 255) / 256, 256, 0, stream>>>(x, emb, h0, N);
  hipMemsetAsync(cnt, 0, (size_t)NSEG * 4, stream);
  int egrid = ((E + 3) / 4 + 255) / 256;
  k_hist<<<egrid, 256, 0, stream>>>(ei, et, cnt, E);
  int nblk = (NSEG + SCAN_CHUNK - 1) / SCAN_CHUNK;
  k_scan_reduce<<<nblk, 256, 0, stream>>>(cnt, blks, NSEG);
  k_scan_top<<<1, 64, 0, stream>>>(blks, nblk, off, NSEG, E);
  k_scan_write<<<nblk, 256, 0, stream>>>(cnt, blks, off, NSEG);
  hipMemcpyAsync(fill, off, (size_t)NSEG * 4, hipMemcpyDeviceToDevice, stream);
  k_scatter<<<egrid, 256, 0, stream>>>(ei, et, fill, sorted, E);

  // ---- fused layers
  int gx = (N + 127) / 128;
  k_fused<false><<<gx, 512, 0, stream>>>(h0, off, sorted, wt, bias, h1, nullptr, N);
  k_fused<true><<<gx, 512, 0, stream>>>(h1, off, sorted, wt + (size_t)NKT * 2048,
                                        bias + DD, nullptr, outf, N);
}

// Round 6
// 554.501 us; speedup vs baseline: 1.4706x; 1.4706x over previous
//
#include <hip/hip_runtime.h>

typedef unsigned int u32;
typedef unsigned short u16;
typedef __attribute__((ext_vector_type(8))) short short8;
typedef __attribute__((ext_vector_type(4))) float f32x4;

#define DD 128
#define RREL 8
#define KCAT 1152  // 128 (h/root) + 8*128 (per-relation aggregated means)
#define NKT 9      // KCAT / 128 k-tiles
#define SCAN_CHUNK 4096

static __device__ __forceinline__ u16 f2bf(float f) {
  u32 u = __builtin_bit_cast(u32, f);
  u32 r = (u + 0x7fffu + ((u >> 16) & 1u)) >> 16;
  return (u16)r;
}
static __device__ __forceinline__ float bflo(u32 v) { return __builtin_bit_cast(float, v << 16); }
static __device__ __forceinline__ float bfhi(u32 v) { return __builtin_bit_cast(float, v & 0xffff0000u); }

// ---- build pre-swizzled transposed weights for linear global_load_lds staging.
// wt[l][kt][pos] (16B chunks): pos = col*16 + cbx holds chunk (col, cb=cbx^(col&7)),
// chunk (col,cb) = 8 bf16 of column `col` at k = kt*128 + cb*8 .. +8, k-space = [root | W0..W7].
__global__ __launch_bounds__(256) void k_convw(const float* __restrict__ W,
                                               const float* __restrict__ root,
                                               uint4* __restrict__ wt) {
  int t = blockIdx.x * 256 + threadIdx.x;
  if (t >= 2 * NKT * 2048) return;
  int l = t / (NKT * 2048);
  int rem = t - l * (NKT * 2048);
  int kt = rem >> 11;
  int pos = rem & 2047;
  int col = pos >> 4;
  int cbx = pos & 15;
  int cb = cbx ^ (col & 7);
  int k0 = kt * DD + cb * 8;
  u16 vals[8];
#pragma unroll
  for (int i = 0; i < 8; ++i) {
    int k = k0 + i;
    float v;
    if (k < DD) {
      v = root[(size_t)l * DD * DD + k * DD + col];
    } else {
      int km = k - DD;
      v = W[((size_t)l * RREL + (km >> 7)) * DD * DD + (size_t)(km & 127) * DD + col];
    }
    vals[i] = f2bf(v);
  }
  wt[t] = *(uint4*)vals;
}

// ---- h0 = bf16(emb[x]) into Acat[node][0:128]
__global__ __launch_bounds__(256) void k_gather(const int* __restrict__ x,
                                                const float* __restrict__ emb,
                                                u16* __restrict__ acat, int N) {
  int t = blockIdx.x * 256 + threadIdx.x;
  if (t >= N * 16) return;
  int node = t >> 4, part = t & 15;
  const float4* e4 = (const float4*)(emb + (size_t)x[node] * DD + part * 8);
  float4 f0 = e4[0], f1 = e4[1];
  uint4 u;
  u.x = (u32)f2bf(f0.x) | ((u32)f2bf(f0.y) << 16);
  u.y = (u32)f2bf(f0.z) | ((u32)f2bf(f0.w) << 16);
  u.z = (u32)f2bf(f1.x) | ((u32)f2bf(f1.y) << 16);
  u.w = (u32)f2bf(f1.z) | ((u32)f2bf(f1.w) << 16);
  *(uint4*)(acat + (size_t)node * KCAT + part * 8) = u;
}

// ---- histogram over segments seg = dst*8 + etype, 8 edges/thread for ILP
__global__ __launch_bounds__(256) void k_hist(const int* __restrict__ ei,
                                              const int* __restrict__ et,
                                              int* __restrict__ cnt, int E) {
  int base = (blockIdx.x * 256 + threadIdx.x) * 8;
  if (base + 7 < E) {
    int4 dA = *(const int4*)(ei + E + base);
    int4 dB = *(const int4*)(ei + E + base + 4);
    int4 tA = *(const int4*)(et + base);
    int4 tB = *(const int4*)(et + base + 4);
    atomicAdd(&cnt[dA.x * 8 + tA.x], 1);
    atomicAdd(&cnt[dA.y * 8 + tA.y], 1);
    atomicAdd(&cnt[dA.z * 8 + tA.z], 1);
    atomicAdd(&cnt[dA.w * 8 + tA.w], 1);
    atomicAdd(&cnt[dB.x * 8 + tB.x], 1);
    atomicAdd(&cnt[dB.y * 8 + tB.y], 1);
    atomicAdd(&cnt[dB.z * 8 + tB.z], 1);
    atomicAdd(&cnt[dB.w * 8 + tB.w], 1);
  } else {
    for (int e = base; e < E; ++e) atomicAdd(&cnt[ei[E + e] * 8 + et[e]], 1);
  }
}

__global__ __launch_bounds__(256) void k_scan_reduce(const int* __restrict__ cnt,
                                                     int* __restrict__ blksum, int nseg) {
  __shared__ int s[256];
  int b = blockIdx.x, t = threadIdx.x;
  int base = b * SCAN_CHUNK;
  int sum = 0;
  for (int i = 0; i < 16; ++i) {
    int idx = base + i * 256 + t;
    if (idx < nseg) sum += cnt[idx];
  }
  s[t] = sum;
  __syncthreads();
  for (int st = 128; st > 0; st >>= 1) {
    if (t < st) s[t] += s[t + st];
    __syncthreads();
  }
  if (t == 0) blksum[b] = s[0];
}

__global__ void k_scan_top(int* __restrict__ blksum, int nblk, int* __restrict__ off,
                           int nseg, int E) {
  if (threadIdx.x == 0 && blockIdx.x == 0) {
    int run = 0;
    for (int b = 0; b < nblk; ++b) { int v = blksum[b]; blksum[b] = run; run += v; }
    off[nseg] = E;
  }
}

__global__ __launch_bounds__(256) void k_scan_write(const int* __restrict__ cnt,
                                                    const int* __restrict__ blksum,
                                                    int* __restrict__ off, int nseg) {
  __shared__ int s[256];
  int b = blockIdx.x, t = threadIdx.x;
  int base = b * SCAN_CHUNK + t * 16;
  int v[16];
  int sum = 0;
#pragma unroll
  for (int i = 0; i < 16; ++i) {
    int idx = base + i;
    v[i] = (idx < nseg) ? cnt[idx] : 0;
    sum += v[i];
  }
  s[t] = sum;
  __syncthreads();
  for (int st = 1; st < 256; st <<= 1) {
    int add = (t >= st) ? s[t - st] : 0;
    __syncthreads();
    s[t] += add;
    __syncthreads();
  }
  int run = blksum[b] + s[t] - sum;
#pragma unroll
  for (int i = 0; i < 16; ++i) {
    int idx = base + i;
    if (idx < nseg) off[idx] = run;
    run += v[i];
  }
}

// ---- scatter: fill starts as a copy of off; pos = atomicAdd(&fill[seg],1). 8 edges/thread.
__global__ __launch_bounds__(256) void k_scatter(const int* __restrict__ ei,
                                                 const int* __restrict__ et,
                                                 int* __restrict__ fill,
                                                 int* __restrict__ sorted, int E) {
  int base = (blockIdx.x * 256 + threadIdx.x) * 8;
  if (base + 7 < E) {
    int4 sA = *(const int4*)(ei + base);
    int4 sB = *(const int4*)(ei + base + 4);
    int4 dA = *(const int4*)(ei + E + base);
    int4 dB = *(const int4*)(ei + E + base + 4);
    int4 tA = *(const int4*)(et + base);
    int4 tB = *(const int4*)(et + base + 4);
    int p0 = atomicAdd(&fill[dA.x * 8 + tA.x], 1);
    int p1 = atomicAdd(&fill[dA.y * 8 + tA.y], 1);
    int p2 = atomicAdd(&fill[dA.z * 8 + tA.z], 1);
    int p3 = atomicAdd(&fill[dA.w * 8 + tA.w], 1);
    int p4 = atomicAdd(&fill[dB.x * 8 + tB.x], 1);
    int p5 = atomicAdd(&fill[dB.y * 8 + tB.y], 1);
    int p6 = atomicAdd(&fill[dB.z * 8 + tB.z], 1);
    int p7 = atomicAdd(&fill[dB.w * 8 + tB.w], 1);
    sorted[p0] = sA.x;
    sorted[p1] = sA.y;
    sorted[p2] = sA.z;
    sorted[p3] = sA.w;
    sorted[p4] = sB.x;
    sorted[p5] = sB.y;
    sorted[p6] = sB.z;
    sorted[p7] = sB.w;
  } else {
    for (int e = base; e < E; ++e) {
      int pos = atomicAdd(&fill[ei[E + e] * 8 + et[e]], 1);
      sorted[pos] = ei[e];
    }
  }
}

static __device__ __forceinline__ void add8(float* a, uint4 v) {
  a[0] += bflo(v.x); a[1] += bfhi(v.x);
  a[2] += bflo(v.y); a[3] += bfhi(v.y);
  a[4] += bflo(v.z); a[5] += bfhi(v.z);
  a[6] += bflo(v.w); a[7] += bfhi(v.w);
}

// ---- aggregation: each 8-lane group walks ONE dst's contiguous 8-relation edge span,
// flushing each relation's mean at its boundary. Relation ends held in a shift register
// of named regs (static indexing, no scratch). Branchless 2-wide edge step.
// Wave balance: max over 8 dsts of total-degree (Poisson(16)) instead of
// max over 8 segments of Poisson(2) -> ~1.7x better lane efficiency.
__global__ __launch_bounds__(256) void k_agg(const int* __restrict__ off,
                                             const int* __restrict__ sorted,
                                             u16* acat, int N, int E) {
  int wave = threadIdx.x >> 6, lane = threadIdx.x & 63;
  int grp = lane >> 3, oct = lane & 7;
  int dst = blockIdx.x * 32 + wave * 8 + grp;
  if (dst >= N) return;
  int4 b0 = *(const int4*)(off + dst * 8);
  int4 b1 = *(const int4*)(off + dst * 8 + 4);
  int je = off[dst * 8 + 8];
  int cs = b0.x;
  int e1 = b0.y, e2 = b0.z, e3 = b0.w, e4 = b1.x, e5 = b1.y, e6 = b1.z, e7 = b1.w, e8 = je;
  u16* ambase = acat + (size_t)dst * KCAT + DD + oct * 16;
  float a[16];
#pragma unroll
  for (int i = 0; i < 16; ++i) a[i] = 0.f;
  int j = cs;
  int r = 0;
  int lastidx = (E > 0) ? E - 1 : 0;
  while (true) {
    // flush finished relations (uniform within the 8-lane group)
    while (r < 8 && j >= e1) {
      int cnt = e1 - cs;
      float norm = (cnt > 0) ? 1.0f / (float)cnt : 0.f;
      uint4 w0, w1;
      w0.x = (u32)f2bf(a[0] * norm) | ((u32)f2bf(a[1] * norm) << 16);
      w0.y = (u32)f2bf(a[2] * norm) | ((u32)f2bf(a[3] * norm) << 16);
      w0.z = (u32)f2bf(a[4] * norm) | ((u32)f2bf(a[5] * norm) << 16);
      w0.w = (u32)f2bf(a[6] * norm) | ((u32)f2bf(a[7] * norm) << 16);
      w1.x = (u32)f2bf(a[8] * norm) | ((u32)f2bf(a[9] * norm) << 16);
      w1.y = (u32)f2bf(a[10] * norm) | ((u32)f2bf(a[11] * norm) << 16);
      w1.z = (u32)f2bf(a[12] * norm) | ((u32)f2bf(a[13] * norm) << 16);
      w1.w = (u32)f2bf(a[14] * norm) | ((u32)f2bf(a[15] * norm) << 16);
      uint4* outp = (uint4*)(ambase + (size_t)r * DD);
      outp[0] = w0;
      outp[1] = w1;
#pragma unroll
      for (int i = 0; i < 16; ++i) a[i] = 0.f;
      cs = e1;
      e1 = e2; e2 = e3; e3 = e4; e4 = e5; e5 = e6; e6 = e7; e7 = e8;
      ++r;
    }
    if (r >= 8) break;
    // branchless 2-wide edge step within current relation
    int j1 = j + 1;
    bool two = (j1 < e1);
    int s0 = sorted[j];
    int s1 = sorted[two ? j1 : lastidx];
    const uint4* p0 = (const uint4*)(acat + (size_t)s0 * KCAT + oct * 16);
    const uint4* p1 = (const uint4*)(acat + (size_t)s1 * KCAT + oct * 16);
    uint4 v0 = p0[0], v0b = p0[1];
    uint4 v1 = p1[0], v1b = p1[1];
    if (!two) {
      v1.x = v1.y = v1.z = v1.w = 0u;
      v1b.x = v1b.y = v1b.z = v1b.w = 0u;
    }
    add8(a, v0); add8(a + 8, v0b);
    add8(a, v1); add8(a + 8, v1b);
    j += two ? 2 : 1;
  }
}

// ---- fused GEMM: out[row] = relu( Acat[row][0:1152] @ Wcat(1152x128) + bias )
// 128 rows/block, 8 waves. B k-tiles (32KB) double-buffered in LDS via async
// global_load_lds (wt is pre-swizzled so linear staging yields the swizzled layout).
// One barrier per k-tile; its implicit vmcnt(0) drain is the load-completion wait.
template <bool LAST>
__global__ __launch_bounds__(512) void k_gemm(u16* acat, const uint4* __restrict__ wt,
                                              const float* __restrict__ bias,
                                              float* __restrict__ dout, int M) {
  __shared__ uint4 ldsB[2][2048];  // 2 x 32KB
  int tid = threadIdx.x, wave = tid >> 6, lane = tid & 63;
  int rowbase = blockIdx.x * 128 + wave * 16;
  int arow = rowbase + (lane & 15);
  int arc = arow < M ? arow : M - 1;
  int klane = (lane >> 4) << 3;
  f32x4 acc[8];
#pragma unroll
  for (int c = 0; c < 8; ++c) acc[c] = (f32x4)0.f;

#define STAGE(KT, BUF)                                                                   \
  do {                                                                                   \
    const uint4* gsrc = wt + (size_t)(KT) * 2048;                                        \
    _Pragma("unroll") for (int i_ = 0; i_ < 4; ++i_) {                                   \
      int cid_ = i_ * 512 + tid;                                                         \
      __builtin_amdgcn_global_load_lds(                                                  \
          (const __attribute__((address_space(1))) uint4*)(gsrc + cid_),                 \
          (__attribute__((address_space(3))) uint4*)&ldsB[BUF][cid_], 16, 0, 0);         \
    }                                                                                    \
  } while (0)

  STAGE(0, 0);
  for (int kt = 0; kt < NKT; ++kt) {
    int cur = kt & 1;
    __syncthreads();  // drains vmcnt -> buf[cur] staged; syncs reuse of buf[cur^1]
    if (kt + 1 < NKT) STAGE(kt + 1, cur ^ 1);
#pragma unroll
    for (int kc = 0; kc < 4; ++kc) {
      short8 a = *(const short8*)(acat + (size_t)arc * KCAT + kt * DD + kc * 32 + klane);
      int chunk = kc * 4 + (lane >> 4);
#pragma unroll
      for (int c = 0; c < 8; ++c) {
        int col = c * 16 + (lane & 15);
        const short8* bp = (const short8*)&ldsB[cur][col * 16 + (chunk ^ (col & 7))];
        acc[c] = __builtin_amdgcn_mfma_f32_16x16x32_bf16(a, *bp, acc[c], 0, 0, 0);
      }
    }
  }
#undef STAGE

  int crow0 = rowbase + ((lane >> 4) << 2);
  int ccol = lane & 15;
#pragma unroll
  for (int c = 0; c < 8; ++c) {
    int col = c * 16 + ccol;
    float bv = bias[col];
#pragma unroll
    for (int i = 0; i < 4; ++i) {
      int row = crow0 + i;
      if (row < M) {
        float v = fmaxf(acc[c][i] + bv, 0.f);
        if (LAST) dout[(size_t)row * DD + col] = v;
        else acat[(size_t)row * KCAT + col] = f2bf(v);
      }
    }
  }
}

extern "C" void kernel_launch(void* const* d_in, const int* in_sizes, int n_in,
                              void* d_out, int out_size, void* d_ws, size_t ws_size,
                              hipStream_t stream) {
  const int* x = (const int*)d_in[0];
  const int* ei = (const int*)d_in[1];
  const int* et = (const int*)d_in[2];
  const float* emb = (const float*)d_in[3];
  const float* W = (const float*)d_in[4];
  const float* root = (const float*)d_in[5];
  const float* bias = (const float*)d_in[6];

  const int N = in_sizes[0];
  const int E = in_sizes[2];
  const int NSEG = N * RREL;

  size_t o = 0;
  auto al = [&](size_t b) { size_t r = o; o = (o + b + 255) & ~(size_t)255; return r; };
  size_t off_o = al(((size_t)NSEG + 1) * 4);
  size_t cnt_o = al((size_t)NSEG * 4);
  size_t fill_o = al((size_t)NSEG * 4);
  size_t sorted_o = al((size_t)E * 4);
  size_t blk_o = al(4096);
  size_t wt_o = al((size_t)2 * NKT * 2048 * 16);
  size_t acat_o = al((size_t)N * KCAT * 2);
  (void)acat_o;

  char* ws = (char*)d_ws;
  int* off = (int*)(ws + off_o);
  int* cnt = (int*)(ws + cnt_o);
  int* fill = (int*)(ws + fill_o);
  int* sorted = (int*)(ws + sorted_o);
  int* blks = (int*)(ws + blk_o);
  uint4* wt = (uint4*)(ws + wt_o);
  u16* acat = (u16*)(ws + acat_o);
  float* outf = (float*)d_out;

  // ---- prep
  k_convw<<<(2 * NKT * 2048 + 255) / 256, 256, 0, stream>>>(W, root, wt);
  k_gather<<<(N * 16 + 255) / 256, 256, 0, stream>>>(x, emb, acat, N);
  hipMemsetAsync(cnt, 0, (size_t)NSEG * 4, stream);
  int egrid = ((E + 7) / 8 + 255) / 256;
  k_hist<<<egrid, 256, 0, stream>>>(ei, et, cnt, E);
  int nblk = (NSEG + SCAN_CHUNK - 1) / SCAN_CHUNK;
  k_scan_reduce<<<nblk, 256, 0, stream>>>(cnt, blks, NSEG);
  k_scan_top<<<1, 64, 0, stream>>>(blks, nblk, off, NSEG, E);
  k_scan_write<<<nblk, 256, 0, stream>>>(cnt, blks, off, NSEG);
  hipMemcpyAsync(fill, off, (size_t)NSEG * 4, hipMemcpyDeviceToDevice, stream);
  k_scatter<<<egrid, 256, 0, stream>>>(ei, et, fill, sorted, E);

  // ---- layers: agg (mean into Acat) then fused GEMM (root+rels+bias+relu)
  int gx = (N + 127) / 128;
  int agrid = (N + 31) / 32;
  k_agg<<<agrid, 256, 0, stream>>>(off, sorted, acat, N, E);
  k_gemm<false><<<gx, 512, 0, stream>>>(acat, wt, bias, nullptr, N);
  k_agg<<<agrid, 256, 0, stream>>>(off, sorted, acat, N, E);
  k_gemm<true><<<gx, 512, 0, stream>>>(acat, wt + (size_t)NKT * 2048, bias + DD, outf, N);
}